// Round 6
// baseline (178.937 us; speedup 1.0000x reference)
//
#include <hip/hip_runtime.h>
#include <hip/hip_bf16.h>
#include <stdint.h>

// Problem constants (from reference setup_inputs)
#define BATCH 8
#define TC 2048   // M
#define TQ 1024   // K
#define DD 1024   // N

typedef __attribute__((ext_vector_type(8))) __bf16 bf16x8;
typedef __attribute__((ext_vector_type(4))) float f32x4;
typedef __attribute__((ext_vector_type(8))) ushort ushort8v;

__device__ __forceinline__ ushort f2bf(float f) {
    uint32_t u = __float_as_uint(f);
    uint32_t r = (u + 0x7fffu + ((u >> 16) & 1u)) >> 16;  // RNE
    return (ushort)r;
}

// ---------------------------------------------------------------------------
// Kernel 1 (fused prep, v3): block types BIT-INTERLEAVED (blockIdx&1) so each
// CU holds softmax AND transpose blocks simultaneously -> transpose LDS/store
// phases fill softmax latency stalls (R5's sequential ID ranges serialized
// the two types per-CU: first ~8 resident blocks all softmax, then all
// transpose -> no mixing; this round tests the mixing hypothesis).
// Internals byte-identical to R5 -> absmax must stay 0.001953125.
//   even blockIdx -> softmax (2048 blocks, 2 rows/wave, ILP-8, 0 LDS)
//   odd  blockIdx -> 64x64 transpose+cast (16.6 KiB LDS)
// ---------------------------------------------------------------------------
__global__ __launch_bounds__(256) void prep2(const float* __restrict__ sim,
                                             const float* __restrict__ qen,
                                             ushort* __restrict__ attn,
                                             ushort* __restrict__ qt) {
    __shared__ float tile[64][65];
    const int t = threadIdx.x;
    if ((blockIdx.x & 1) == 0) {
        // ---- softmax: 2 rows per wave, whole rows in registers ----
        const int sb = blockIdx.x >> 1;            // 0..2047
        const int wid = t >> 6, lane = t & 63;
        const int r0 = sb * 8 + wid * 2;           // 4 waves x 2 rows

        const float4* s0 = (const float4*)(sim + (size_t)r0 * TQ);
        const float4* s1 = (const float4*)(sim + (size_t)(r0 + 1) * TQ);

        float4 x0[4], x1[4];
        #pragma unroll
        for (int j = 0; j < 4; j++) { x0[j] = s0[lane + 64 * j]; x1[j] = s1[lane + 64 * j]; }

        float m0 = -INFINITY, m1 = -INFINITY;
        #pragma unroll
        for (int j = 0; j < 4; j++) {
            m0 = fmaxf(m0, fmaxf(fmaxf(x0[j].x, x0[j].y), fmaxf(x0[j].z, x0[j].w)));
            m1 = fmaxf(m1, fmaxf(fmaxf(x1[j].x, x1[j].y), fmaxf(x1[j].z, x1[j].w)));
        }
        #pragma unroll
        for (int o = 32; o >= 1; o >>= 1) {
            m0 = fmaxf(m0, __shfl_xor(m0, o));
            m1 = fmaxf(m1, __shfl_xor(m1, o));
        }

        const float L2E = 1.4426950408889634f;
        float sa = 0.f, sb2 = 0.f;
        #pragma unroll
        for (int j = 0; j < 4; j++) {
            x0[j].x = exp2f((x0[j].x - m0) * L2E);
            x0[j].y = exp2f((x0[j].y - m0) * L2E);
            x0[j].z = exp2f((x0[j].z - m0) * L2E);
            x0[j].w = exp2f((x0[j].w - m0) * L2E);
            sa += (x0[j].x + x0[j].y) + (x0[j].z + x0[j].w);
            x1[j].x = exp2f((x1[j].x - m1) * L2E);
            x1[j].y = exp2f((x1[j].y - m1) * L2E);
            x1[j].z = exp2f((x1[j].z - m1) * L2E);
            x1[j].w = exp2f((x1[j].w - m1) * L2E);
            sb2 += (x1[j].x + x1[j].y) + (x1[j].z + x1[j].w);
        }
        #pragma unroll
        for (int o = 32; o >= 1; o >>= 1) {
            sa += __shfl_xor(sa, o);
            sb2 += __shfl_xor(sb2, o);
        }
        const float iva = 1.0f / sa, ivb = 1.0f / sb2;

        ushort4* d0 = (ushort4*)(attn + (size_t)r0 * TQ);
        ushort4* d1 = (ushort4*)(attn + (size_t)(r0 + 1) * TQ);
        #pragma unroll
        for (int j = 0; j < 4; j++) {
            ushort4 o4;
            o4.x = f2bf(x0[j].x * iva);
            o4.y = f2bf(x0[j].y * iva);
            o4.z = f2bf(x0[j].z * iva);
            o4.w = f2bf(x0[j].w * iva);
            d0[lane + 64 * j] = o4;
            o4.x = f2bf(x1[j].x * ivb);
            o4.y = f2bf(x1[j].y * ivb);
            o4.z = f2bf(x1[j].z * ivb);
            o4.w = f2bf(x1[j].w * ivb);
            d1[lane + 64 * j] = o4;
        }
    } else {
        // ---- transpose+cast: qencode [b][q][d] fp32 -> qt [b][d][q] bf16 ----
        const int bid = blockIdx.x >> 1;    // 0..2047
        const int b = bid >> 8;             // 256 tiles per batch (16x16)
        const int rem = bid & 255;
        const int q0 = (rem >> 4) * 64;
        const int d0 = (rem & 15) * 64;
        const int r = t >> 4;               // 0..15
        const int c = (t & 15) * 4;         // 0..60

        #pragma unroll
        for (int it = 0; it < 4; it++) {
            float4 v = *(const float4*)(qen + ((size_t)b * TQ + q0 + r + it * 16) * DD + d0 + c);
            tile[r + it * 16][c + 0] = v.x;
            tile[r + it * 16][c + 1] = v.y;
            tile[r + it * 16][c + 2] = v.z;
            tile[r + it * 16][c + 3] = v.w;
        }
        __syncthreads();

        #pragma unroll
        for (int it = 0; it < 4; it++) {
            const int d = (t >> 4) + it * 16;
            const int qq = (t & 15) * 4;
            ushort4 o4;
            o4.x = f2bf(tile[qq + 0][d]);
            o4.y = f2bf(tile[qq + 1][d]);
            o4.z = f2bf(tile[qq + 2][d]);
            o4.w = f2bf(tile[qq + 3][d]);
            *(ushort4*)(qt + ((size_t)b * DD + d0 + d) * TQ + q0 + qq) = o4;
        }
    }
}

// ---------------------------------------------------------------------------
// Kernel 2: batched GEMM  C[b] = A[b] (MxK bf16) x Bt[b]^T (NxK bf16)
// R4 configuration VERBATIM (proven <=40.6us): 128x128 / BK=64 / 4 waves,
// plain f32 stores, __launch_bounds__(256,2), batch-per-XCD decode
// (b = flat&7 -> HW round-robin gives each XCD one batch; FETCH 66->25MB).
// R5's nontemporal stores REVERTED (they inflated WRITE_SIZE 65.6->81MB,
// partial-line HBM writes) and (256,4) REVERTED (occupancy unmoved).
// ---------------------------------------------------------------------------
__global__ __launch_bounds__(256, 2) void gemm_bf16(const ushort* __restrict__ A,
                                                    const ushort* __restrict__ Bt,
                                                    float* __restrict__ C) {
    __shared__ __align__(16) ushort As[128 * 64];   // 16 KiB
    __shared__ __align__(16) ushort Bs[128 * 64];   // 16 KiB

    const int flat = blockIdx.x;
    const int b = flat & 7;           // batch = XCD (dispatch round-robin)
    const int rem = flat >> 3;        // 0..127: 16 m-tiles x 8 n-tiles
    const int group = rem >> 5;       // 4 groups of 32 blocks
    const int mi_t = group * 4 + (rem & 3);
    const int ni_t = (rem >> 2) & 7;
    const int tm0 = mi_t * 128;
    const int tn0 = ni_t * 128;

    const ushort* Ab = A + (size_t)b * TC * TQ;
    const ushort* Bb = Bt + (size_t)b * DD * TQ;
    float* Cb = C + (size_t)b * TC * DD;

    const int t = threadIdx.x;
    const int w = t >> 6, lane = t & 63;
    const int quad = lane >> 4, l16 = lane & 15;
    const int wm = (w >> 1) * 64, wn = (w & 1) * 64;

    f32x4 acc[4][4];
    #pragma unroll
    for (int i = 0; i < 4; i++)
        #pragma unroll
        for (int j = 0; j < 4; j++) acc[i][j] = (f32x4){0.f, 0.f, 0.f, 0.f};

    // staging: chunk idx = i*256 + w*64 + lane; row = idx>>3 = i*32+w*8+(lane>>3)
    // slot-chunk xs = lane&7; fetch global chunk c = xs ^ (row&7)
    const int srow = w * 8 + (lane >> 3);
    const int sk = ((lane & 7) ^ (lane >> 3)) * 8;   // ushort offset in k

    // fragment read: row = frag_base + l16 (frag_base % 16 == 0), so row&7 = l16&7
    const int rkey = l16 & 7;

    for (int kk = 0; kk < TQ; kk += 64) {
        #pragma unroll
        for (int i = 0; i < 4; i++) {
            const ushort* ga = Ab + (size_t)(tm0 + i * 32 + srow) * TQ + kk + sk;
            const ushort* gb = Bb + (size_t)(tn0 + i * 32 + srow) * TQ + kk + sk;
            char* la = (char*)As + i * 4096 + w * 1024;
            char* lb = (char*)Bs + i * 4096 + w * 1024;
            __builtin_amdgcn_global_load_lds(
                (const __attribute__((address_space(1))) void*)ga,
                (__attribute__((address_space(3))) void*)la, 16, 0, 0);
            __builtin_amdgcn_global_load_lds(
                (const __attribute__((address_space(1))) void*)gb,
                (__attribute__((address_space(3))) void*)lb, 16, 0, 0);
        }
        __syncthreads();

        #pragma unroll
        for (int s = 0; s < 2; s++) {
            const int rswz = ((s * 4 + quad) ^ rkey) * 8;   // ushort offset
            bf16x8 af[4], bfr[4];
            #pragma unroll
            for (int mi = 0; mi < 4; mi++)
                af[mi] = *(const bf16x8*)&As[(wm + mi * 16 + l16) * 64 + rswz];
            #pragma unroll
            for (int ni = 0; ni < 4; ni++)
                bfr[ni] = *(const bf16x8*)&Bs[(wn + ni * 16 + l16) * 64 + rswz];

            #pragma unroll
            for (int mi = 0; mi < 4; mi++)
                #pragma unroll
                for (int ni = 0; ni < 4; ni++)
                    acc[mi][ni] = __builtin_amdgcn_mfma_f32_16x16x32_bf16(
                        af[mi], bfr[ni], acc[mi][ni], 0, 0, 0);
        }
        __syncthreads();
    }

    // epilogue: C/D layout col=lane&15, row=quad*4+reg
    #pragma unroll
    for (int mi = 0; mi < 4; mi++) {
        const int r0 = tm0 + wm + mi * 16 + quad * 4;
        #pragma unroll
        for (int ni = 0; ni < 4; ni++) {
            const int c = tn0 + wn + ni * 16 + l16;
            f32x4 v = acc[mi][ni];
            #pragma unroll
            for (int r = 0; r < 4; r++) Cb[(size_t)(r0 + r) * DD + c] = v[r];
        }
    }
}

// ---------------------------------------------------------------------------
extern "C" void kernel_launch(void* const* d_in, const int* in_sizes, int n_in,
                              void* d_out, int out_size, void* d_ws, size_t ws_size,
                              hipStream_t stream) {
    const float* sim = (const float*)d_in[0];   // [8, 2048, 1024]
    const float* qen = (const float*)d_in[1];   // [8, 1024, 1024]
    float* out = (float*)d_out;                 // [8, 2048, 1024]

    ushort* attn = (ushort*)d_ws;                                  // 32 MiB bf16
    ushort* qt = (ushort*)d_ws + (size_t)BATCH * TC * TQ;          // 16 MiB bf16

    prep2<<<4096, 256, 0, stream>>>(sim, qen, attn, qt);
    gemm_bf16<<<BATCH * (TC / 128) * (DD / 128), 256, 0, stream>>>(attn, qt, out);
}

// Round 7
// 178.279 us; speedup vs baseline: 1.0037x; 1.0037x over previous
//
#include <hip/hip_runtime.h>
#include <hip/hip_bf16.h>
#include <stdint.h>

// Problem constants (from reference setup_inputs)
#define BATCH 8
#define TC 2048   // M
#define TQ 1024   // K
#define DD 1024   // N

typedef __attribute__((ext_vector_type(8))) __bf16 bf16x8;
typedef __attribute__((ext_vector_type(4))) float f32x4;
typedef __attribute__((ext_vector_type(8))) ushort ushort8v;

__device__ __forceinline__ ushort f2bf(float f) {
    uint32_t u = __float_as_uint(f);
    uint32_t r = (u + 0x7fffu + ((u >> 16) & 1u)) >> 16;  // RNE
    return (ushort)r;
}

// ---------------------------------------------------------------------------
// Kernel 1 (prep v4, pipelined persistent waves): R7 hypothesis = prep was
// ISSUE-SHAPE limited: one-shot waves do {8-load burst -> ~900cy drain ->
// serial reduce/exp/store with ZERO outstanding loads -> exit}, so the CU's
// memory pipe idles during all compute phases (VALUBusy 16%, HBM 26%, occ 51%
// -> none of the classic limits).  Fix: each wave runs 4 iterations with
// 1-deep register prefetch -- next iteration's 8 global loads issue BEFORE
// the current reduce/exp/store -- keeping loads in flight continuously.
//   blocks [0,512):   softmax, 4 waves x 2 rows x 4 iters  (32 rows/block)
//   blocks [512,1024): transpose, 4 tiles/block, prefetch across syncthreads
// All math bit-identical to R6 -> absmax must stay 0.001953125.
// ---------------------------------------------------------------------------
__global__ __launch_bounds__(256) void prep3(const float* __restrict__ sim,
                                             const float* __restrict__ qen,
                                             ushort* __restrict__ attn,
                                             ushort* __restrict__ qt) {
    __shared__ float tile[64][65];
    const int t = threadIdx.x;
    if (blockIdx.x < 512) {
        // ---- softmax: 2 rows/wave/iter, 4 iters, 1-deep prefetch ----
        const int wid = t >> 6, lane = t & 63;
        const int pair0 = blockIdx.x * 16 + wid * 4;       // 4 consecutive pairs
        const float4* sp = (const float4*)(sim + (size_t)pair0 * 2 * TQ);
        ushort4* dp = (ushort4*)(attn + (size_t)pair0 * 2 * TQ);
        const float L2E = 1.4426950408889634f;

        float4 x0[4], x1[4], n0[4], n1[4];
        #pragma unroll
        for (int j = 0; j < 4; j++) {
            x0[j] = sp[lane + 64 * j];
            x1[j] = sp[256 + lane + 64 * j];
        }

        #pragma unroll
        for (int n = 0; n < 4; n++) {
            // issue next pair's loads BEFORE current compute (latency hides
            // under reduce/exp/store; waitcnt lands at next iter's first use)
            if (n < 3) {
                const float4* np = sp + 512;
                #pragma unroll
                for (int j = 0; j < 4; j++) {
                    n0[j] = np[lane + 64 * j];
                    n1[j] = np[256 + lane + 64 * j];
                }
            }

            float m0 = -INFINITY, m1 = -INFINITY;
            #pragma unroll
            for (int j = 0; j < 4; j++) {
                m0 = fmaxf(m0, fmaxf(fmaxf(x0[j].x, x0[j].y), fmaxf(x0[j].z, x0[j].w)));
                m1 = fmaxf(m1, fmaxf(fmaxf(x1[j].x, x1[j].y), fmaxf(x1[j].z, x1[j].w)));
            }
            #pragma unroll
            for (int o = 32; o >= 1; o >>= 1) {
                m0 = fmaxf(m0, __shfl_xor(m0, o));
                m1 = fmaxf(m1, __shfl_xor(m1, o));
            }

            float sa = 0.f, sb = 0.f;
            #pragma unroll
            for (int j = 0; j < 4; j++) {
                x0[j].x = exp2f((x0[j].x - m0) * L2E);
                x0[j].y = exp2f((x0[j].y - m0) * L2E);
                x0[j].z = exp2f((x0[j].z - m0) * L2E);
                x0[j].w = exp2f((x0[j].w - m0) * L2E);
                sa += (x0[j].x + x0[j].y) + (x0[j].z + x0[j].w);
                x1[j].x = exp2f((x1[j].x - m1) * L2E);
                x1[j].y = exp2f((x1[j].y - m1) * L2E);
                x1[j].z = exp2f((x1[j].z - m1) * L2E);
                x1[j].w = exp2f((x1[j].w - m1) * L2E);
                sb += (x1[j].x + x1[j].y) + (x1[j].z + x1[j].w);
            }
            #pragma unroll
            for (int o = 32; o >= 1; o >>= 1) {
                sa += __shfl_xor(sa, o);
                sb += __shfl_xor(sb, o);
            }
            const float iva = 1.0f / sa, ivb = 1.0f / sb;

            #pragma unroll
            for (int j = 0; j < 4; j++) {
                ushort4 o4;
                o4.x = f2bf(x0[j].x * iva);
                o4.y = f2bf(x0[j].y * iva);
                o4.z = f2bf(x0[j].z * iva);
                o4.w = f2bf(x0[j].w * iva);
                dp[lane + 64 * j] = o4;
                o4.x = f2bf(x1[j].x * ivb);
                o4.y = f2bf(x1[j].y * ivb);
                o4.z = f2bf(x1[j].z * ivb);
                o4.w = f2bf(x1[j].w * ivb);
                dp[256 + lane + 64 * j] = o4;
            }

            sp += 512;
            dp += 512;
            if (n < 3) {
                #pragma unroll
                for (int j = 0; j < 4; j++) { x0[j] = n0[j]; x1[j] = n1[j]; }
            }
        }
    } else {
        // ---- transpose+cast: 4 tiles/block, prefetch across the LDS phase ----
        const int tb = blockIdx.x - 512;
        const int r = t >> 4;               // 0..15
        const int c = (t & 15) * 4;         // 0..60
        const int dl = t >> 4;              // output d sub-index
        const int qq = (t & 15) * 4;

        float4 v[4], v2[4];
        {
            const int tile_i = tb * 4;
            const int b = tile_i >> 8;
            const int rem = tile_i & 255;
            const int q0 = (rem >> 4) * 64;
            const int d0 = (rem & 15) * 64;
            #pragma unroll
            for (int it = 0; it < 4; it++)
                v[it] = *(const float4*)(qen + ((size_t)b * TQ + q0 + r + it * 16) * DD + d0 + c);
        }

        #pragma unroll
        for (int n = 0; n < 4; n++) {
            const int tile_i = tb * 4 + n;
            const int b = tile_i >> 8;
            const int rem = tile_i & 255;
            const int q0 = (rem >> 4) * 64;
            const int d0 = (rem & 15) * 64;

            #pragma unroll
            for (int it = 0; it < 4; it++) {
                tile[r + it * 16][c + 0] = v[it].x;
                tile[r + it * 16][c + 1] = v[it].y;
                tile[r + it * 16][c + 2] = v[it].z;
                tile[r + it * 16][c + 3] = v[it].w;
            }

            // issue next tile's global loads before the syncthreads; they sit
            // in vmcnt across the LDS-read/store phase (regs only, no hazard)
            if (n < 3) {
                const int tj = tile_i + 1;
                const int b2 = tj >> 8;
                const int rem2 = tj & 255;
                const int q02 = (rem2 >> 4) * 64;
                const int d02 = (rem2 & 15) * 64;
                #pragma unroll
                for (int it = 0; it < 4; it++)
                    v2[it] = *(const float4*)(qen + ((size_t)b2 * TQ + q02 + r + it * 16) * DD + d02 + c);
            }

            __syncthreads();

            #pragma unroll
            for (int it = 0; it < 4; it++) {
                const int d = dl + it * 16;
                ushort4 o4;
                o4.x = f2bf(tile[qq + 0][d]);
                o4.y = f2bf(tile[qq + 1][d]);
                o4.z = f2bf(tile[qq + 2][d]);
                o4.w = f2bf(tile[qq + 3][d]);
                *(ushort4*)(qt + ((size_t)b * DD + d0 + d) * TQ + q0 + qq) = o4;
            }

            if (n < 3) {
                __syncthreads();   // protect LDS overwrite next iter
                #pragma unroll
                for (int it = 0; it < 4; it++) v[it] = v2[it];
            }
        }
    }
}

// ---------------------------------------------------------------------------
// Kernel 2: batched GEMM  C[b] = A[b] (MxK bf16) x Bt[b]^T (NxK bf16)
// R4/R6 configuration VERBATIM (proven <=43us, stable): 128x128 / BK=64 /
// 4 waves, plain f32 stores, __launch_bounds__(256,2), batch-per-XCD decode.
// ---------------------------------------------------------------------------
__global__ __launch_bounds__(256, 2) void gemm_bf16(const ushort* __restrict__ A,
                                                    const ushort* __restrict__ Bt,
                                                    float* __restrict__ C) {
    __shared__ __align__(16) ushort As[128 * 64];   // 16 KiB
    __shared__ __align__(16) ushort Bs[128 * 64];   // 16 KiB

    const int flat = blockIdx.x;
    const int b = flat & 7;           // batch = XCD (dispatch round-robin)
    const int rem = flat >> 3;        // 0..127: 16 m-tiles x 8 n-tiles
    const int group = rem >> 5;       // 4 groups of 32 blocks
    const int mi_t = group * 4 + (rem & 3);
    const int ni_t = (rem >> 2) & 7;
    const int tm0 = mi_t * 128;
    const int tn0 = ni_t * 128;

    const ushort* Ab = A + (size_t)b * TC * TQ;
    const ushort* Bb = Bt + (size_t)b * DD * TQ;
    float* Cb = C + (size_t)b * TC * DD;

    const int t = threadIdx.x;
    const int w = t >> 6, lane = t & 63;
    const int quad = lane >> 4, l16 = lane & 15;
    const int wm = (w >> 1) * 64, wn = (w & 1) * 64;

    f32x4 acc[4][4];
    #pragma unroll
    for (int i = 0; i < 4; i++)
        #pragma unroll
        for (int j = 0; j < 4; j++) acc[i][j] = (f32x4){0.f, 0.f, 0.f, 0.f};

    // staging: chunk idx = i*256 + w*64 + lane; row = idx>>3 = i*32+w*8+(lane>>3)
    // slot-chunk xs = lane&7; fetch global chunk c = xs ^ (row&7)
    const int srow = w * 8 + (lane >> 3);
    const int sk = ((lane & 7) ^ (lane >> 3)) * 8;   // ushort offset in k

    // fragment read: row = frag_base + l16 (frag_base % 16 == 0), so row&7 = l16&7
    const int rkey = l16 & 7;

    for (int kk = 0; kk < TQ; kk += 64) {
        #pragma unroll
        for (int i = 0; i < 4; i++) {
            const ushort* ga = Ab + (size_t)(tm0 + i * 32 + srow) * TQ + kk + sk;
            const ushort* gb = Bb + (size_t)(tn0 + i * 32 + srow) * TQ + kk + sk;
            char* la = (char*)As + i * 4096 + w * 1024;
            char* lb = (char*)Bs + i * 4096 + w * 1024;
            __builtin_amdgcn_global_load_lds(
                (const __attribute__((address_space(1))) void*)ga,
                (__attribute__((address_space(3))) void*)la, 16, 0, 0);
            __builtin_amdgcn_global_load_lds(
                (const __attribute__((address_space(1))) void*)gb,
                (__attribute__((address_space(3))) void*)lb, 16, 0, 0);
        }
        __syncthreads();

        #pragma unroll
        for (int s = 0; s < 2; s++) {
            const int rswz = ((s * 4 + quad) ^ rkey) * 8;   // ushort offset
            bf16x8 af[4], bfr[4];
            #pragma unroll
            for (int mi = 0; mi < 4; mi++)
                af[mi] = *(const bf16x8*)&As[(wm + mi * 16 + l16) * 64 + rswz];
            #pragma unroll
            for (int ni = 0; ni < 4; ni++)
                bfr[ni] = *(const bf16x8*)&Bs[(wn + ni * 16 + l16) * 64 + rswz];

            #pragma unroll
            for (int mi = 0; mi < 4; mi++)
                #pragma unroll
                for (int ni = 0; ni < 4; ni++)
                    acc[mi][ni] = __builtin_amdgcn_mfma_f32_16x16x32_bf16(
                        af[mi], bfr[ni], acc[mi][ni], 0, 0, 0);
        }
        __syncthreads();
    }

    // epilogue: C/D layout col=lane&15, row=quad*4+reg
    #pragma unroll
    for (int mi = 0; mi < 4; mi++) {
        const int r0 = tm0 + wm + mi * 16 + quad * 4;
        #pragma unroll
        for (int ni = 0; ni < 4; ni++) {
            const int c = tn0 + wn + ni * 16 + l16;
            f32x4 v = acc[mi][ni];
            #pragma unroll
            for (int r = 0; r < 4; r++) Cb[(size_t)(r0 + r) * DD + c] = v[r];
        }
    }
}

// ---------------------------------------------------------------------------
extern "C" void kernel_launch(void* const* d_in, const int* in_sizes, int n_in,
                              void* d_out, int out_size, void* d_ws, size_t ws_size,
                              hipStream_t stream) {
    const float* sim = (const float*)d_in[0];   // [8, 2048, 1024]
    const float* qen = (const float*)d_in[1];   // [8, 1024, 1024]
    float* out = (float*)d_out;                 // [8, 2048, 1024]

    ushort* attn = (ushort*)d_ws;                                  // 32 MiB bf16
    ushort* qt = (ushort*)d_ws + (size_t)BATCH * TC * TQ;          // 16 MiB bf16

    prep3<<<512 + 512, 256, 0, stream>>>(sim, qen, attn, qt);
    gemm_bf16<<<BATCH * (TC / 128) * (DD / 128), 256, 0, stream>>>(attn, qt, out);
}